// Round 1
// 357.304 us; speedup vs baseline: 1.0033x; 1.0033x over previous
//
#include <hip/hip_runtime.h>
#include <stdint.h>

// PixCorr R6: remove the per-block vmcnt(0) drain entirely.
// R5 measured ~115us (~3.5 TB/s) for the 402.7MB stream while the harness's
// own fillBuffer dispatches hit 6.7 TB/s on the same path. The stall is the
// __syncthreads() after the DMA batch: compiler lowers it as
// s_waitcnt vmcnt(0) + s_barrier -> full drain, once per block, x12288.
// R6: persistent independent waves (no barrier in the hot loop), per-wave
// double-buffered LDS ping-pong with COUNTED vmcnt (T3/T4: never drain to 0):
//   wait vmcnt(8) -> ds_read_b128 x8 -> lgkmcnt(0) -> issue next 8 DMAs
//   into the just-read buffer -> fp64 accumulate.
// 512 blocks x 256 thr = 2048 waves = exactly 2 blocks/CU (64KiB LDS each),
// single full-resident launch. Outstanding >= 64KiB/CU at all times.

typedef float f4 __attribute__((ext_vector_type(4)));

constexpr int    NROWS    = 256;
constexpr int    D        = 3 * 256 * 256;      // 196608 floats per row
constexpr int    D4       = D / 4;              // 49152 float4 per row
constexpr int    TPB      = 256;                // 4 waves/block
constexpr int    WPB      = TPB / 64;           // 4
constexpr int    WPR      = 8;                  // waves per row
constexpr int    NBLOCKS  = NROWS * WPR / WPB;  // 512 == 2 blocks/CU exactly
constexpr int    K        = 4;                  // float4 per lane per array per stage
constexpr int    STAGE_F4 = 64 * K;             // 256 float4 per array per stage
constexpr int    WAVE_F4  = D4 / WPR;           // 6144 float4 per wave per array
constexpr int    NSTAGES  = WAVE_F4 / STAGE_F4; // 24
constexpr double EPS      = 1e-6;

__device__ __forceinline__ void async_ld16(const void* g, void* l) {
    // nt cache policy (bit1): pure stream, no reuse (R3's win).
    __builtin_amdgcn_global_load_lds(
        (const __attribute__((address_space(1))) uint32_t*)g,
        (__attribute__((address_space(3))) uint32_t*)l,
        16, 0, 2);
}

// partials layout: [gwave][5] doubles, gwave = row*8 + seg  (2048*5 doubles).
__global__ __launch_bounds__(TPB, 2) void partial_kernel(
        const f4* __restrict__ preds,
        const f4* __restrict__ targets,
        double* __restrict__ partials)
{
    // [wave][buf][arr][u][lane] : 4*2*2*4*64*16B = 64 KiB. arr0=preds(B), arr1=targets(Z).
    __shared__ f4 sBuf[WPB][2][2][K][64];

    const int  tid  = threadIdx.x;
    const int  w    = tid >> 6;          // wave id (lane-uniform)
    const int  lane = tid & 63;
    const int  gw   = blockIdx.x * WPB + w;
    const int  row  = gw >> 3;           // gw / WPR
    const int  seg  = gw & (WPR - 1);
    const long gbase = (long)row * D4 + (long)seg * WAVE_F4;

    // Issue one stage's 8 async 1KiB DMAs. LDS dest is wave-uniform base;
    // HW adds lane*16, landing at sBuf[w][p][arr][u][lane] (identity map).
    auto issue = [&](int t, int p) {
        const long gb = gbase + (long)t * STAGE_F4;
        #pragma unroll
        for (int u = 0; u < K; ++u) {
            async_ld16(&preds[gb + u * 64 + lane],   &sBuf[w][p][0][u][0]);
            async_ld16(&targets[gb + u * 64 + lane], &sBuf[w][p][1][u][0]);
        }
    };

    issue(0, 0);
    issue(1, 1);   // 16 DMAs outstanding

    double sZ = 0, sB = 0, sZZ = 0, sBB = 0, sZB = 0;

    auto accum = [&](const f4* bv, const f4* zv) {
        #pragma unroll
        for (int u = 0; u < K; ++u) {
            #pragma unroll
            for (int c = 0; c < 4; ++c) {
                const double b = (double)bv[u][c];
                const double z = (double)zv[u][c];
                sZ += z; sB += b;
                sZZ = fma(z, z, sZZ);
                sBB = fma(b, b, sBB);
                sZB = fma(z, b, sZB);
            }
        }
    };

    for (int t = 0; t < NSTAGES - 1; ++t) {
        const int p = t & 1;
        // Counted wait: stage t's 8 DMAs done; stage t+1's 8 still in flight.
        asm volatile("s_waitcnt vmcnt(8)" ::: "memory");
        __builtin_amdgcn_sched_barrier(0);
        f4 bv[K], zv[K];
        #pragma unroll
        for (int u = 0; u < K; ++u) {
            bv[u] = sBuf[w][p][0][u][lane];
            zv[u] = sBuf[w][p][1][u][lane];
        }
        // Reads must complete before the same buffer is overwritten.
        asm volatile("s_waitcnt lgkmcnt(0)" ::: "memory");
        __builtin_amdgcn_sched_barrier(0);
        if (t + 2 < NSTAGES) issue(t + 2, p);
        accum(bv, zv);
    }
    {   // last stage: drain fully (epilogue only)
        const int p = (NSTAGES - 1) & 1;
        asm volatile("s_waitcnt vmcnt(0)" ::: "memory");
        __builtin_amdgcn_sched_barrier(0);
        f4 bv[K], zv[K];
        #pragma unroll
        for (int u = 0; u < K; ++u) {
            bv[u] = sBuf[w][p][0][u][lane];
            zv[u] = sBuf[w][p][1][u][lane];
        }
        asm volatile("s_waitcnt lgkmcnt(0)" ::: "memory");
        accum(bv, zv);
    }

    // Wave (64-lane) shuffle reduction; waves are fully independent -> no LDS
    // cross-wave step, no __syncthreads in this kernel at all.
    #pragma unroll
    for (int off = 32; off > 0; off >>= 1) {
        sZ  += __shfl_down(sZ,  off);
        sB  += __shfl_down(sB,  off);
        sZZ += __shfl_down(sZZ, off);
        sBB += __shfl_down(sBB, off);
        sZB += __shfl_down(sZB, off);
    }
    if (lane == 0) {
        double* o = partials + (long)gw * 5;
        o[0] = sZ; o[1] = sB; o[2] = sZZ; o[3] = sBB; o[4] = sZB;
    }
}

// One thread per row: sum its 8 wave-partials (40 contiguous doubles),
// compute the row correlation, then block-reduce the mean. Single launch
// replaces row_reduce + mean.
__global__ __launch_bounds__(NROWS) void finalize_kernel(
        const double* __restrict__ partials, float* __restrict__ out)
{
    const int r = threadIdx.x;
    const double* p = partials + (long)r * WPR * 5;
    double tZ = 0, tB = 0, tZZ = 0, tBB = 0, tZB = 0;
    #pragma unroll
    for (int s = 0; s < WPR; ++s) {
        tB  += p[s * 5 + 1 - 1 + 0];  // p[s*5+0] = sZ? (arr order: o[0]=sZ)
        // -- explicit to avoid confusion:
    }
    // redo cleanly (compiler folds the dead loop above away is not guaranteed;
    // just compute directly):
    tZ = 0; tB = 0; tZZ = 0; tBB = 0; tZB = 0;
    #pragma unroll
    for (int s = 0; s < WPR; ++s) {
        tZ  += p[s * 5 + 0];
        tB  += p[s * 5 + 1];
        tZZ += p[s * 5 + 2];
        tBB += p[s * 5 + 3];
        tZB += p[s * 5 + 4];
    }
    const double invD = 1.0 / (double)D;
    const double num  = tZB - tZ * tB * invD;
    const double varZ = fmax(tZZ - tZ * tZ * invD, 0.0);
    const double varB = fmax(tBB - tB * tB * invD, 0.0);
    const double den  = sqrt(varZ) * sqrt(varB) + EPS;
    double corr = num / den;

    #pragma unroll
    for (int off = 32; off > 0; off >>= 1) corr += __shfl_down(corr, off);

    __shared__ double sm[NROWS / 64];
    const int wave = r >> 6;
    const int lane = r & 63;
    if (lane == 0) sm[wave] = corr;
    __syncthreads();
    if (r == 0) {
        double t = 0.0;
        #pragma unroll
        for (int v = 0; v < NROWS / 64; ++v) t += sm[v];
        out[0] = (float)(t / (double)NROWS);
    }
}

extern "C" void kernel_launch(void* const* d_in, const int* in_sizes, int n_in,
                              void* d_out, int out_size, void* d_ws, size_t ws_size,
                              hipStream_t stream) {
    const f4* preds   = (const f4*)d_in[0];
    const f4* targets = (const f4*)d_in[1];
    double* partials  = (double*)d_ws;     // 2048*5 doubles = 80 KiB
    float*  out       = (float*)d_out;

    hipLaunchKernelGGL(partial_kernel, dim3(NBLOCKS), dim3(TPB), 0, stream,
                       preds, targets, partials);
    hipLaunchKernelGGL(finalize_kernel, dim3(1), dim3(NROWS), 0, stream,
                       partials, out);
}